// Round 1
// baseline (375.371 us; speedup 1.0000x reference)
//
#include <hip/hip_runtime.h>

#define B_ 8
#define N_ 4096
#define C_ 512
#define H_ 8
#define HD_ 64

typedef _Float16 h8  __attribute__((ext_vector_type(8)));
typedef _Float16 h4v __attribute__((ext_vector_type(4)));
typedef float    f4  __attribute__((ext_vector_type(4)));

// ---- workspace layout (bytes) ----
static const size_t OFF_COS  = 0;                                   // 4 MiB  f32 [4096][256]
static const size_t OFF_SIN  = (size_t)4*1024*1024;                 // 4 MiB
static const size_t OFF_KRT  = (size_t)8*1024*1024;                 // 32 MiB f16 [64bh][64d][4096n]
static const size_t OFF_VT   = (size_t)40*1024*1024;                // 32 MiB f16 [64bh][64e][4096n]
static const size_t OFF_KSUM = (size_t)72*1024*1024;                // 16 KiB f32 [8][512]
static const size_t OFF_Z    = (size_t)72*1024*1024 + 64*1024;      // 1 MiB  f32 [8][4096][8]
static const size_t OFF_KVP  = (size_t)73*1024*1024 + 64*1024;      // 8 MiB  f32 [8sp][64bh][64][64]

__device__ inline unsigned int pack2h(float a, float b){
    union { _Float16 h[2]; unsigned int u; } x;
    x.h[0] = (_Float16)a; x.h[1] = (_Float16)b; return x.u;
}

// ---- cos/sin tables: angle = n * base^(-j/256) (mimic f32 reference rounding) ----
__global__ void k_tables(float* __restrict__ cosT, float* __restrict__ sinT){
    int n = blockIdx.x, j = threadIdx.x;
    double th = exp((double)j * -0.035977892078031970); // ln(1e4)/256
    float ang = (float)n * (float)th;
    float s, c; sincosf(ang, &s, &c);
    cosT[n*256 + j] = c; sinT[n*256 + j] = s;
}

// ---- y -> vT[bh][e][n] f16 transpose ----
__global__ __launch_bounds__(256) void k_vt(const float* __restrict__ y, _Float16* __restrict__ vT){
    int nt = blockIdx.x, h = blockIdx.y, b = blockIdx.z;
    int t = threadIdx.x;
    int e = t >> 2, ns = t & 3;
    int n0 = nt*64 + ns*16;
    const float* yp = y + ((size_t)(b*N_ + n0))*C_ + h*HD_ + e;
    float v[16];
#pragma unroll
    for (int i=0;i<16;++i) v[i] = yp[(size_t)i*C_];
    unsigned int u[8];
#pragma unroll
    for (int i=0;i<8;++i) u[i] = pack2h(v[2*i], v[2*i+1]);
    _Float16* dst = vT + ((size_t)((b*H_ + h)*HD_ + e))*N_ + n0;
    uint4* p = (uint4*)dst;
    p[0] = make_uint4(u[0],u[1],u[2],u[3]);
    p[1] = make_uint4(u[4],u[5],u[6],u[7]);
}

// ---- fused GEMM (+bias, elu+1, rope, ksum/z) ----
// C[m][j] = sum_k X[m][k] * W[j][k];  128x128 tile, 4 waves, 16x16x32 f16 MFMA
template<int IS_Q>
__global__ __launch_bounds__(256) void k_gemm(
    const float* __restrict__ X, const float* __restrict__ W, const float* __restrict__ bias,
    float* qrOut, _Float16* krT, float* ksum, float* zbuf, const float* ksumIn,
    const float* __restrict__ cosT, const float* __restrict__ sinT)
{
    __shared__ _Float16 As[128*40];   // rows=x rows, 32 k + pad(8)
    __shared__ _Float16 Bs[128*40];   // rows=out channels j
    const int t = threadIdx.x;
    const int lane = t & 63;
    const int w = t >> 6;
    const int wm = w >> 1, wn = w & 1;
    const int col0 = blockIdx.x * 128;
    const int row0 = blockIdx.y * 128;
    const int lrow = lane & 15, lg = lane >> 4;
    const int srow = t >> 3;
    const int sc4 = (t & 7) * 4;

    f4 acc[4][4] = {};

    const float* Xp = X + (size_t)(row0 + srow)*C_ + sc4;
    const float* Wp = W + (size_t)(col0 + srow)*C_ + sc4;
    float4 ra[4], rb[4];
#pragma unroll
    for (int it=0; it<4; ++it){
        ra[it] = *(const float4*)(Xp + (size_t)it*32*C_);
        rb[it] = *(const float4*)(Wp + (size_t)it*32*C_);
    }

    for (int kk=0; kk<16; ++kk){
        __syncthreads();
#pragma unroll
        for (int it=0; it<4; ++it){
            int r = srow + it*32;
            h4v a; a[0]=(_Float16)ra[it].x; a[1]=(_Float16)ra[it].y; a[2]=(_Float16)ra[it].z; a[3]=(_Float16)ra[it].w;
            *(h4v*)&As[r*40 + sc4] = a;
            h4v bb; bb[0]=(_Float16)rb[it].x; bb[1]=(_Float16)rb[it].y; bb[2]=(_Float16)rb[it].z; bb[3]=(_Float16)rb[it].w;
            *(h4v*)&Bs[r*40 + sc4] = bb;
        }
        __syncthreads();
        if (kk < 15){
#pragma unroll
            for (int it=0; it<4; ++it){
                ra[it] = *(const float4*)(Xp + (size_t)it*32*C_ + (kk+1)*32);
                rb[it] = *(const float4*)(Wp + (size_t)it*32*C_ + (kk+1)*32);
            }
        }
        h8 af[4], bf[4];
#pragma unroll
        for (int mi=0; mi<4; ++mi) af[mi] = *(const h8*)&As[(wm*64 + mi*16 + lrow)*40 + lg*8];
#pragma unroll
        for (int ni=0; ni<4; ++ni) bf[ni] = *(const h8*)&Bs[(wn*64 + ni*16 + lrow)*40 + lg*8];
#pragma unroll
        for (int mi=0; mi<4; ++mi)
#pragma unroll
            for (int ni=0; ni<4; ++ni)
                acc[mi][ni] = __builtin_amdgcn_mfma_f32_16x16x32_f16(af[mi], bf[ni], acc[mi][ni], 0, 0, 0);
    }

    // ---- epilogue ----
    const int b = row0 >> 12;
    const int hcol0 = col0 + wn*64;     // wave spans exactly one head
    const int h = hcol0 >> 6;
    float bcol[4], km[4];
#pragma unroll
    for (int ni=0; ni<4; ++ni){
        int c = hcol0 + ni*16 + lrow;
        bcol[ni] = bias[c];
        km[ni] = IS_Q ? ksumIn[b*C_ + c] * (1.0f/4096.0f) : 0.0f;
    }
    float colsum[4] = {0.f,0.f,0.f,0.f};

#pragma unroll
    for (int mi=0; mi<4; ++mi){
        float qv[4][4];
#pragma unroll
        for (int ni=0; ni<4; ++ni)
#pragma unroll
            for (int r=0; r<4; ++r){
                float v = acc[mi][ni][r] + bcol[ni];
                qv[ni][r] = v > 0.f ? v + 1.f : __expf(v);   // elu(v)+1
            }
        if (IS_Q){
#pragma unroll
            for (int r=0; r<4; ++r){
                float p = qv[0][r]*km[0] + qv[1][r]*km[1] + qv[2][r]*km[2] + qv[3][r]*km[3];
                p += __shfl_xor(p, 1); p += __shfl_xor(p, 2);
                p += __shfl_xor(p, 4); p += __shfl_xor(p, 8);
                if (lrow == 0){
                    int grow = row0 + wm*64 + mi*16 + lg*4 + r;
                    zbuf[(size_t)grow*8 + h] = 1.0f / (p + 1e-6f);
                }
            }
        } else {
#pragma unroll
            for (int ni=0; ni<4; ++ni)
                colsum[ni] += qv[ni][0]+qv[ni][1]+qv[ni][2]+qv[ni][3];
        }
        // rope + store
#pragma unroll
        for (int ni=0; ni<4; ++ni){
            int c = hcol0 + ni*16 + lrow;
            int jj = c >> 1;
#pragma unroll
            for (int r=0; r<4; ++r){
                int grow = row0 + wm*64 + mi*16 + lg*4 + r;
                int n = grow & (N_-1);
                float val = qv[ni][r];
                float par = __shfl_xor(val, 1);
                float cs = cosT[n*256 + jj], sn = sinT[n*256 + jj];
                float rv = (lane & 1) ? fmaf(sn, par, cs*val) : fmaf(cs, val, -sn*par);
                if (IS_Q){
                    float prv = __shfl_xor(rv, 1);
                    if (!(lane & 1)){
                        float2 st; st.x = rv; st.y = prv;
                        *(float2*)&qrOut[(size_t)grow*C_ + c] = st;
                    }
                } else {
                    int d = c & 63;
                    krT[((size_t)(b*H_ + h)*HD_ + d)*N_ + n] = (_Float16)rv;
                }
            }
        }
    }
    if (!IS_Q){
#pragma unroll
        for (int ni=0; ni<4; ++ni){
            float s = colsum[ni];
            s += __shfl_xor(s, 16); s += __shfl_xor(s, 32);
            if (lane < 16) atomicAdd(&ksum[b*C_ + hcol0 + ni*16 + lane], s);
        }
    }
}

// ---- kv partials: kv[d][e] = (1/N) sum_n krT[d][n]*vT[e][n], split over n ----
__global__ __launch_bounds__(256) void k_kv(
    const _Float16* __restrict__ krT, const _Float16* __restrict__ vT, float* __restrict__ kvp)
{
    __shared__ float kvs[4096];
    const int split = blockIdx.x, h = blockIdx.y, b = blockIdx.z;
    const int bh = b*H_ + h;
    const int t = threadIdx.x, lane = t & 63, w = t >> 6;
    for (int i=t; i<4096; i+=256) kvs[i] = 0.f;
    __syncthreads();
    const int lrow = lane & 15, lg = lane >> 4;
    const _Float16* ka = krT + (size_t)bh*HD_*N_;
    const _Float16* vb = vT  + (size_t)bh*HD_*N_;
    f4 acc[4][4] = {};
    const int nbase = split*512 + w*128;
#pragma unroll
    for (int ks=0; ks<4; ++ks){
        int n0 = nbase + ks*32 + lg*8;
        h8 af[4], bf[4];
#pragma unroll
        for (int mi=0; mi<4; ++mi) af[mi] = *(const h8*)&ka[(size_t)(mi*16+lrow)*N_ + n0];
#pragma unroll
        for (int ni=0; ni<4; ++ni) bf[ni] = *(const h8*)&vb[(size_t)(ni*16+lrow)*N_ + n0];
#pragma unroll
        for (int mi=0; mi<4; ++mi)
#pragma unroll
            for (int ni=0; ni<4; ++ni)
                acc[mi][ni] = __builtin_amdgcn_mfma_f32_16x16x32_f16(af[mi], bf[ni], acc[mi][ni], 0,0,0);
    }
#pragma unroll
    for (int mi=0; mi<4; ++mi)
#pragma unroll
        for (int ni=0; ni<4; ++ni)
#pragma unroll
            for (int r=0; r<4; ++r){
                int d = mi*16 + lg*4 + r, e = ni*16 + lrow;
                atomicAdd(&kvs[d*64 + e], acc[mi][ni][r] * (1.0f/4096.0f));
            }
    __syncthreads();
    float* o = kvp + ((size_t)(split*64 + bh))*4096;
    for (int i=t; i<4096; i+=256) o[i] = kvs[i];
}

// ---- out = (q_rope @ kv) * z + lepe ;  qr lives in d_out and is overwritten ----
__global__ __launch_bounds__(256) void k_out(
    const float* qr, const float* __restrict__ y, const float* __restrict__ zbuf,
    const float* __restrict__ kvp, const float* __restrict__ lw, const float* __restrict__ lb,
    float* outp)
{
    __shared__ _Float16 qrs[256*72];
    __shared__ _Float16 kvT[64*72];
    __shared__ float lws[64*4];
    const int chunk = blockIdx.x, h = blockIdx.y, b = blockIdx.z;
    const int bh = b*H_ + h;
    const int t = threadIdx.x, lane = t & 63, w = t >> 6;
    const int r0 = chunk * 256;

    { // kv: sum 8 partials, store transposed f16 [e][d]
        int d = t >> 2, e0 = (t & 3) * 16;
#pragma unroll
        for (int i=0;i<16;++i){
            float s = 0.f;
#pragma unroll
            for (int sp=0; sp<8; ++sp) s += kvp[((size_t)(sp*64 + bh))*4096 + d*64 + e0 + i];
            kvT[(e0+i)*72 + d] = (_Float16)s;
        }
    }
    for (int ii=0; ii<16; ++ii){ // qr rows -> f16 LDS
        int idx = t + ii*256;
        int r = idx >> 4, d4 = (idx & 15)*4;
        float4 v = *(const float4*)&qr[((size_t)(b*N_ + r0 + r))*C_ + h*HD_ + d4];
        h4v hv; hv[0]=(_Float16)v.x; hv[1]=(_Float16)v.y; hv[2]=(_Float16)v.z; hv[3]=(_Float16)v.w;
        *(h4v*)&qrs[r*72 + d4] = hv;
    }
    if (t < 64){
        lws[t*4+0] = lw[(h*HD_+t)*3 + 0];
        lws[t*4+1] = lw[(h*HD_+t)*3 + 1];
        lws[t*4+2] = lw[(h*HD_+t)*3 + 2];
        lws[t*4+3] = lb[h*HD_+t];
    }
    __syncthreads();

    const int lrow = lane & 15, lg = lane >> 4;
    f4 acc[4][4] = {};
#pragma unroll
    for (int ks=0; ks<2; ++ks){
        h8 af[4], bf[4];
#pragma unroll
        for (int mi=0; mi<4; ++mi) af[mi] = *(const h8*)&qrs[(w*64 + mi*16 + lrow)*72 + ks*32 + lg*8];
#pragma unroll
        for (int ni=0; ni<4; ++ni) bf[ni] = *(const h8*)&kvT[(ni*16 + lrow)*72 + ks*32 + lg*8];
#pragma unroll
        for (int mi=0; mi<4; ++mi)
#pragma unroll
            for (int ni=0; ni<4; ++ni)
                acc[mi][ni] = __builtin_amdgcn_mfma_f32_16x16x32_f16(af[mi], bf[ni], acc[mi][ni], 0,0,0);
    }

#pragma unroll
    for (int mi=0; mi<4; ++mi){
#pragma unroll
        for (int r=0; r<4; ++r){
            int n = r0 + w*64 + mi*16 + lg*4 + r;
            size_t g = (size_t)b*N_ + n;
            float zv = zbuf[g*8 + h];
#pragma unroll
            for (int ni=0; ni<4; ++ni){
                int e = ni*16 + lrow;
                int c = h*HD_ + e;
                float4 wv = *(const float4*)&lws[e*4];
                float s = fmaf(y[g*C_ + c], wv.y, wv.w);
                if (n > 0)     s = fmaf(y[(g-1)*C_ + c], wv.x, s);
                if (n < N_-1)  s = fmaf(y[(g+1)*C_ + c], wv.z, s);
                outp[g*C_ + c] = fmaf(acc[mi][ni][r], zv, s);
            }
        }
    }
}

extern "C" void kernel_launch(void* const* d_in, const int* in_sizes, int n_in,
                              void* d_out, int out_size, void* d_ws, size_t ws_size,
                              hipStream_t stream)
{
    (void)in_sizes; (void)n_in; (void)out_size; (void)ws_size;
    const float* x  = (const float*)d_in[0];
    const float* y  = (const float*)d_in[1];
    const float* Wq = (const float*)d_in[2];
    const float* bq = (const float*)d_in[3];
    const float* Wk = (const float*)d_in[4];
    const float* bk = (const float*)d_in[5];
    const float* lw = (const float*)d_in[6];
    const float* lb = (const float*)d_in[7];

    char* ws = (char*)d_ws;
    float*    cosT = (float*)(ws + OFF_COS);
    float*    sinT = (float*)(ws + OFF_SIN);
    _Float16* krT  = (_Float16*)(ws + OFF_KRT);
    _Float16* vT   = (_Float16*)(ws + OFF_VT);
    float*    ksum = (float*)(ws + OFF_KSUM);
    float*    zbuf = (float*)(ws + OFF_Z);
    float*    kvp  = (float*)(ws + OFF_KVP);
    float*    out  = (float*)d_out;

    hipMemsetAsync(ws + OFF_KSUM, 0, 16384, stream);
    k_tables<<<dim3(N_), dim3(256), 0, stream>>>(cosT, sinT);
    k_vt<<<dim3(64, H_, B_), dim3(256), 0, stream>>>(y, vT);
    // k first (produces ksum for q's z-epilogue)
    k_gemm<0><<<dim3(4, 256), dim3(256), 0, stream>>>(y, Wk, bk, nullptr, krT, ksum, nullptr, nullptr, cosT, sinT);
    k_gemm<1><<<dim3(4, 256), dim3(256), 0, stream>>>(x, Wq, bq, out, nullptr, nullptr, zbuf, ksum, cosT, sinT);
    k_kv<<<dim3(8, H_, B_), dim3(256), 0, stream>>>(krT, vT, kvp);
    k_out<<<dim3(16, H_, B_), dim3(256), 0, stream>>>(out, y, zbuf, kvp, lw, lb, out);
}

// Round 2
// 280.244 us; speedup vs baseline: 1.3394x; 1.3394x over previous
//
#include <hip/hip_runtime.h>

#define B_ 8
#define N_ 4096
#define C_ 512
#define H_ 8
#define HD_ 64

typedef _Float16 h8  __attribute__((ext_vector_type(8)));
typedef _Float16 h4v __attribute__((ext_vector_type(4)));
typedef float    f4  __attribute__((ext_vector_type(4)));

// ---- workspace layout (bytes) ----
static const size_t OFF_COS  = 0;                                   // 4 MiB  f32 [4096][256]
static const size_t OFF_SIN  = (size_t)4*1024*1024;                 // 4 MiB
static const size_t OFF_KRT  = (size_t)8*1024*1024;                 // 32 MiB f16 [64bh][64d][4096n]
static const size_t OFF_VT   = (size_t)40*1024*1024;                // 32 MiB f16 [64bh][64e][4096n]
static const size_t OFF_KSUM = (size_t)72*1024*1024;                // 16 KiB f32 [8][512]
static const size_t OFF_Z    = (size_t)72*1024*1024 + 64*1024;      // 1 MiB  f32 [8][4096][8]
static const size_t OFF_KVP  = (size_t)73*1024*1024 + 64*1024;      // 8 MiB  f32 [8sp][64bh][64][64]
static const size_t OFF_KVT  = (size_t)81*1024*1024 + 64*1024;      // 512 KiB f16 [64bh][64e][64d]

__device__ inline unsigned int pack2h(float a, float b){
    union { _Float16 h[2]; unsigned int u; } x;
    x.h[0] = (_Float16)a; x.h[1] = (_Float16)b; return x.u;
}

// ---- cos/sin tables ----
__global__ void k_tables(float* __restrict__ cosT, float* __restrict__ sinT){
    int n = blockIdx.x, j = threadIdx.x;
    double th = exp((double)j * -0.035977892078031970); // ln(1e4)/256
    float ang = (float)n * (float)th;
    float s, c; sincosf(ang, &s, &c);
    cosT[n*256 + j] = c; sinT[n*256 + j] = s;
}

// ---- y -> vT[bh][e][n] f16, LDS-tiled transpose ----
__global__ __launch_bounds__(256) void k_vt(const float* __restrict__ y, _Float16* __restrict__ vT){
    __shared__ float tile[64*65];
    int nt = blockIdx.x, h = blockIdx.y, b = blockIdx.z;
    int t = threadIdx.x;
    int n0 = nt*64;
#pragma unroll
    for (int ii=0; ii<4; ++ii){
        int i = t + ii*256;
        int r = i >> 4, c4 = (i & 15)*4;
        float4 v = *(const float4*)&y[((size_t)(b*N_ + n0 + r))*C_ + h*HD_ + c4];
        tile[r*65+c4+0]=v.x; tile[r*65+c4+1]=v.y; tile[r*65+c4+2]=v.z; tile[r*65+c4+3]=v.w;
    }
    __syncthreads();
    int e = t >> 2, ns = (t & 3) * 16;
    unsigned int u[8];
#pragma unroll
    for (int i=0;i<8;++i)
        u[i] = pack2h(tile[(ns+2*i)*65 + e], tile[(ns+2*i+1)*65 + e]);
    _Float16* dst = vT + ((size_t)((b*H_ + h)*HD_ + e))*N_ + n0 + ns;
    uint4* p = (uint4*)dst;
    p[0] = make_uint4(u[0],u[1],u[2],u[3]);
    p[1] = make_uint4(u[4],u[5],u[6],u[7]);
}

// ---- fused GEMM (+bias, elu+1, rope, ksum/z) ----
template<int IS_Q>
__global__ __launch_bounds__(256) void k_gemm(
    const float* __restrict__ X, const float* __restrict__ W, const float* __restrict__ bias,
    float* qrOut, _Float16* krT, float* ksum, float* zbuf, const float* ksumIn,
    const float* __restrict__ cosT, const float* __restrict__ sinT)
{
    __shared__ _Float16 As[128*40];
    __shared__ _Float16 Bs[128*40];
    const int t = threadIdx.x;
    const int lane = t & 63;
    const int w = t >> 6;
    const int wm = w >> 1, wn = w & 1;
    const int col0 = blockIdx.x * 128;
    const int row0 = blockIdx.y * 128;
    const int lrow = lane & 15, lg = lane >> 4;
    const int srow = t >> 3;
    const int sc4 = (t & 7) * 4;

    f4 acc[4][4] = {};

    const float* Xp = X + (size_t)(row0 + srow)*C_ + sc4;
    const float* Wp = W + (size_t)(col0 + srow)*C_ + sc4;
    float4 ra[4], rb[4];
#pragma unroll
    for (int it=0; it<4; ++it){
        ra[it] = *(const float4*)(Xp + (size_t)it*32*C_);
        rb[it] = *(const float4*)(Wp + (size_t)it*32*C_);
    }

    for (int kk=0; kk<16; ++kk){
        __syncthreads();
#pragma unroll
        for (int it=0; it<4; ++it){
            int r = srow + it*32;
            h4v a; a[0]=(_Float16)ra[it].x; a[1]=(_Float16)ra[it].y; a[2]=(_Float16)ra[it].z; a[3]=(_Float16)ra[it].w;
            *(h4v*)&As[r*40 + sc4] = a;
            h4v bb; bb[0]=(_Float16)rb[it].x; bb[1]=(_Float16)rb[it].y; bb[2]=(_Float16)rb[it].z; bb[3]=(_Float16)rb[it].w;
            *(h4v*)&Bs[r*40 + sc4] = bb;
        }
        __syncthreads();
        if (kk < 15){
#pragma unroll
            for (int it=0; it<4; ++it){
                ra[it] = *(const float4*)(Xp + (size_t)it*32*C_ + (kk+1)*32);
                rb[it] = *(const float4*)(Wp + (size_t)it*32*C_ + (kk+1)*32);
            }
        }
        h8 af[4], bf[4];
#pragma unroll
        for (int mi=0; mi<4; ++mi) af[mi] = *(const h8*)&As[(wm*64 + mi*16 + lrow)*40 + lg*8];
#pragma unroll
        for (int ni=0; ni<4; ++ni) bf[ni] = *(const h8*)&Bs[(wn*64 + ni*16 + lrow)*40 + lg*8];
#pragma unroll
        for (int mi=0; mi<4; ++mi)
#pragma unroll
            for (int ni=0; ni<4; ++ni)
                acc[mi][ni] = __builtin_amdgcn_mfma_f32_16x16x32_f16(af[mi], bf[ni], acc[mi][ni], 0, 0, 0);
    }

    const int b = row0 >> 12;
    const int hcol0 = col0 + wn*64;
    const int h = hcol0 >> 6;
    float bcol[4], km[4];
#pragma unroll
    for (int ni=0; ni<4; ++ni){
        int c = hcol0 + ni*16 + lrow;
        bcol[ni] = bias[c];
        km[ni] = IS_Q ? ksumIn[b*C_ + c] * (1.0f/4096.0f) : 0.0f;
    }
    float colsum[4] = {0.f,0.f,0.f,0.f};

#pragma unroll
    for (int mi=0; mi<4; ++mi){
        float qv[4][4];
#pragma unroll
        for (int ni=0; ni<4; ++ni)
#pragma unroll
            for (int r=0; r<4; ++r){
                float v = acc[mi][ni][r] + bcol[ni];
                qv[ni][r] = v > 0.f ? v + 1.f : __expf(v);
            }
        if (IS_Q){
#pragma unroll
            for (int r=0; r<4; ++r){
                float p = qv[0][r]*km[0] + qv[1][r]*km[1] + qv[2][r]*km[2] + qv[3][r]*km[3];
                p += __shfl_xor(p, 1); p += __shfl_xor(p, 2);
                p += __shfl_xor(p, 4); p += __shfl_xor(p, 8);
                if (lrow == 0){
                    int grow = row0 + wm*64 + mi*16 + lg*4 + r;
                    zbuf[(size_t)grow*8 + h] = 1.0f / (p + 1e-6f);
                }
            }
        } else {
#pragma unroll
            for (int ni=0; ni<4; ++ni)
                colsum[ni] += qv[ni][0]+qv[ni][1]+qv[ni][2]+qv[ni][3];
        }
#pragma unroll
        for (int ni=0; ni<4; ++ni){
            int c = hcol0 + ni*16 + lrow;
            int jj = c >> 1;
#pragma unroll
            for (int r=0; r<4; ++r){
                int grow = row0 + wm*64 + mi*16 + lg*4 + r;
                int n = grow & (N_-1);
                float val = qv[ni][r];
                float par = __shfl_xor(val, 1);
                float cs = cosT[n*256 + jj], sn = sinT[n*256 + jj];
                float rv = (lane & 1) ? fmaf(sn, par, cs*val) : fmaf(cs, val, -sn*par);
                if (IS_Q){
                    float prv = __shfl_xor(rv, 1);
                    if (!(lane & 1)){
                        float2 st; st.x = rv; st.y = prv;
                        *(float2*)&qrOut[(size_t)grow*C_ + c] = st;
                    }
                } else {
                    int d = c & 63;
                    krT[((size_t)(b*H_ + h)*HD_ + d)*N_ + n] = (_Float16)rv;
                }
            }
        }
    }
    if (!IS_Q){
#pragma unroll
        for (int ni=0; ni<4; ++ni){
            float s = colsum[ni];
            s += __shfl_xor(s, 16); s += __shfl_xor(s, 32);
            if (lane < 16) atomicAdd(&ksum[b*C_ + hcol0 + ni*16 + lane], s);
        }
    }
}

// ---- kv partials ----
__global__ __launch_bounds__(256) void k_kv(
    const _Float16* __restrict__ krT, const _Float16* __restrict__ vT, float* __restrict__ kvp)
{
    __shared__ float kvs[4096];
    const int split = blockIdx.x, h = blockIdx.y, b = blockIdx.z;
    const int bh = b*H_ + h;
    const int t = threadIdx.x, lane = t & 63, w = t >> 6;
    for (int i=t; i<4096; i+=256) kvs[i] = 0.f;
    __syncthreads();
    const int lrow = lane & 15, lg = lane >> 4;
    const _Float16* ka = krT + (size_t)bh*HD_*N_;
    const _Float16* vb = vT  + (size_t)bh*HD_*N_;
    f4 acc[4][4] = {};
    const int nbase = split*512 + w*128;
#pragma unroll
    for (int ks=0; ks<4; ++ks){
        int n0 = nbase + ks*32 + lg*8;
        h8 af[4], bf[4];
#pragma unroll
        for (int mi=0; mi<4; ++mi) af[mi] = *(const h8*)&ka[(size_t)(mi*16+lrow)*N_ + n0];
#pragma unroll
        for (int ni=0; ni<4; ++ni) bf[ni] = *(const h8*)&vb[(size_t)(ni*16+lrow)*N_ + n0];
#pragma unroll
        for (int mi=0; mi<4; ++mi)
#pragma unroll
            for (int ni=0; ni<4; ++ni)
                acc[mi][ni] = __builtin_amdgcn_mfma_f32_16x16x32_f16(af[mi], bf[ni], acc[mi][ni], 0,0,0);
    }
#pragma unroll
    for (int mi=0; mi<4; ++mi)
#pragma unroll
        for (int ni=0; ni<4; ++ni)
#pragma unroll
            for (int r=0; r<4; ++r){
                int d = mi*16 + lg*4 + r, e = ni*16 + lrow;
                atomicAdd(&kvs[d*64 + e], acc[mi][ni][r] * (1.0f/4096.0f));
            }
    __syncthreads();
    float* o = kvp + ((size_t)(split*64 + bh))*4096;
    for (int i=t; i<4096; i+=256) o[i] = kvs[i];
}

// ---- merge kv partials -> f16 kvT[bh][e][d] ----
__global__ __launch_bounds__(256) void k_kvmerge(const float* __restrict__ kvp, _Float16* __restrict__ kvTg){
    __shared__ float kvs[64*65];
    int bh = blockIdx.x;
    int t = threadIdx.x;
    int base = t*16;
    f4 s0={},s1={},s2={},s3={};
#pragma unroll
    for (int sp=0; sp<8; ++sp){
        const float* p = kvp + ((size_t)(sp*64 + bh))*4096 + base;
        s0 += *(const f4*)(p+0); s1 += *(const f4*)(p+4);
        s2 += *(const f4*)(p+8); s3 += *(const f4*)(p+12);
    }
    int d = t>>2, e0 = (t&3)*16;
#pragma unroll
    for (int j=0;j<4;++j){
        kvs[d*65+e0+j]=s0[j]; kvs[d*65+e0+4+j]=s1[j];
        kvs[d*65+e0+8+j]=s2[j]; kvs[d*65+e0+12+j]=s3[j];
    }
    __syncthreads();
    int e = t>>2, d0 = (t&3)*16;
    unsigned int u[8];
#pragma unroll
    for (int i=0;i<8;++i) u[i] = pack2h(kvs[(d0+2*i)*65+e], kvs[(d0+2*i+1)*65+e]);
    uint4* dst = (uint4*)(kvTg + (size_t)bh*4096 + e*64 + d0);
    dst[0] = make_uint4(u[0],u[1],u[2],u[3]);
    dst[1] = make_uint4(u[4],u[5],u[6],u[7]);
}

// ---- out = (q_rope @ kv) * z + lepe; two-phase, 64 rows/block ----
__global__ __launch_bounds__(256) void k_out(
    const float* __restrict__ qr, const float* __restrict__ y,
    const float* __restrict__ zbuf, const _Float16* __restrict__ kvTg,
    const float* __restrict__ lw, const float* __restrict__ lb,
    float* __restrict__ outp)
{
    __shared__ __align__(16) char smem[18432];
    _Float16* qrs  = (_Float16*)smem;            // [64][72] f16
    _Float16* kvs  = (_Float16*)(smem + 9216);   // [64][72] f16 [e][d]
    float*    accs = (float*)smem;               // [64][68] f32, aliases (post-MFMA)
    const int chunk = blockIdx.x, h = blockIdx.y, b = blockIdx.z;
    const int bh = b*H_ + h;
    const int t = threadIdx.x, lane = t & 63, w = t >> 6;
    const int r0 = chunk * 64;

    // lepe weights to regs (c4 thread-invariant)
    const int c4 = (t & 15) * 4;
    float w0[4], w1[4], w2[4], wb[4];
#pragma unroll
    for (int j=0;j<4;++j){
        int cc = h*HD_ + c4 + j;
        w0[j]=lw[cc*3+0]; w1[j]=lw[cc*3+1]; w2[j]=lw[cc*3+2]; wb[j]=lb[cc];
    }

    // stage kv [e][d]
#pragma unroll
    for (int p=0;p<2;++p){
        int idx = t*8 + p*2048;
        int e = idx>>6, d0 = idx&63;
        *(uint4*)&kvs[e*72+d0] = *(const uint4*)&kvTg[(size_t)bh*4096 + idx];
    }
    // stage qr rows -> f16
#pragma unroll
    for (int ii=0; ii<4; ++ii){
        int i = t + ii*256;
        int r = i>>4, cc4 = (i&15)*4;
        float4 v = *(const float4*)&qr[((size_t)(b*N_ + r0 + r))*C_ + h*HD_ + cc4];
        h4v hv; hv[0]=(_Float16)v.x; hv[1]=(_Float16)v.y; hv[2]=(_Float16)v.z; hv[3]=(_Float16)v.w;
        *(h4v*)&qrs[r*72 + cc4] = hv;
    }
    __syncthreads();

    const int lrow = lane & 15, lg = lane >> 4;
    f4 acc[4] = {};
#pragma unroll
    for (int ks=0; ks<2; ++ks){
        h8 af = *(const h8*)&qrs[(w*16 + lrow)*72 + ks*32 + lg*8];
#pragma unroll
        for (int ni=0; ni<4; ++ni){
            h8 bf = *(const h8*)&kvs[(ni*16 + lrow)*72 + ks*32 + lg*8];
            acc[ni] = __builtin_amdgcn_mfma_f32_16x16x32_f16(af, bf, acc[ni], 0,0,0);
        }
    }
    __syncthreads();
#pragma unroll
    for (int ni=0; ni<4; ++ni)
#pragma unroll
        for (int r=0; r<4; ++r)
            accs[(w*16 + lg*4 + r)*68 + ni*16 + lrow] = acc[ni][r];
    __syncthreads();

    const int rl = t >> 4;
#pragma unroll
    for (int ii=0; ii<4; ++ii){
        int row = rl + ii*16;
        int n = r0 + row;
        size_t g = (size_t)b*N_ + n;
        float z = zbuf[g*8 + h];
        f4 a = *(f4*)&accs[row*68 + c4];
        const float* yp = y + g*C_ + h*HD_ + c4;
        float4 y1 = *(const float4*)yp;
        float s0 = fmaf(y1.x, w1[0], wb[0]);
        float s1 = fmaf(y1.y, w1[1], wb[1]);
        float s2 = fmaf(y1.z, w1[2], wb[2]);
        float s3 = fmaf(y1.w, w1[3], wb[3]);
        if (n > 0){
            float4 y0 = *(const float4*)(yp - C_);
            s0 = fmaf(y0.x, w0[0], s0); s1 = fmaf(y0.y, w0[1], s1);
            s2 = fmaf(y0.z, w0[2], s2); s3 = fmaf(y0.w, w0[3], s3);
        }
        if (n < N_-1){
            float4 y2 = *(const float4*)(yp + C_);
            s0 = fmaf(y2.x, w2[0], s0); s1 = fmaf(y2.y, w2[1], s1);
            s2 = fmaf(y2.z, w2[2], s2); s3 = fmaf(y2.w, w2[3], s3);
        }
        float4 o;
        o.x = fmaf(a[0], z, s0); o.y = fmaf(a[1], z, s1);
        o.z = fmaf(a[2], z, s2); o.w = fmaf(a[3], z, s3);
        *(float4*)&outp[g*C_ + h*HD_ + c4] = o;
    }
}

extern "C" void kernel_launch(void* const* d_in, const int* in_sizes, int n_in,
                              void* d_out, int out_size, void* d_ws, size_t ws_size,
                              hipStream_t stream)
{
    (void)in_sizes; (void)n_in; (void)out_size; (void)ws_size;
    const float* x  = (const float*)d_in[0];
    const float* y  = (const float*)d_in[1];
    const float* Wq = (const float*)d_in[2];
    const float* bq = (const float*)d_in[3];
    const float* Wk = (const float*)d_in[4];
    const float* bk = (const float*)d_in[5];
    const float* lw = (const float*)d_in[6];
    const float* lb = (const float*)d_in[7];

    char* ws = (char*)d_ws;
    float*    cosT = (float*)(ws + OFF_COS);
    float*    sinT = (float*)(ws + OFF_SIN);
    _Float16* krT  = (_Float16*)(ws + OFF_KRT);
    _Float16* vT   = (_Float16*)(ws + OFF_VT);
    float*    ksum = (float*)(ws + OFF_KSUM);
    float*    zbuf = (float*)(ws + OFF_Z);
    float*    kvp  = (float*)(ws + OFF_KVP);
    _Float16* kvTg = (_Float16*)(ws + OFF_KVT);
    float*    out  = (float*)d_out;

    hipMemsetAsync(ws + OFF_KSUM, 0, 16384, stream);
    k_tables<<<dim3(N_), dim3(256), 0, stream>>>(cosT, sinT);
    k_vt<<<dim3(64, H_, B_), dim3(256), 0, stream>>>(y, vT);
    k_gemm<0><<<dim3(4, 256), dim3(256), 0, stream>>>(y, Wk, bk, nullptr, krT, ksum, nullptr, nullptr, cosT, sinT);
    k_gemm<1><<<dim3(4, 256), dim3(256), 0, stream>>>(x, Wq, bq, out, nullptr, nullptr, zbuf, ksum, cosT, sinT);
    k_kv<<<dim3(8, H_, B_), dim3(256), 0, stream>>>(krT, vT, kvp);
    k_kvmerge<<<dim3(64), dim3(256), 0, stream>>>(kvp, kvTg);
    k_out<<<dim3(64, H_, B_), dim3(256), 0, stream>>>(out, y, zbuf, kvTg, lw, lb, out);
}

// Round 3
// 199.499 us; speedup vs baseline: 1.8816x; 1.4047x over previous
//
#include <hip/hip_runtime.h>

#define B_ 8
#define N_ 4096
#define C_ 512
#define H_ 8

typedef _Float16 h8  __attribute__((ext_vector_type(8)));
typedef _Float16 h4v __attribute__((ext_vector_type(4)));
typedef float    f4  __attribute__((ext_vector_type(4)));

// ---- workspace layout (bytes) ----
static const size_t OFF_COS  = 0;                                  // 4 MiB f32 [4096][256]
static const size_t OFF_SIN  = (size_t)4*1024*1024;                // 4 MiB
static const size_t OFF_KRH  = (size_t)8*1024*1024;                // 32 MiB f16 [B*N][C] k_rope
static const size_t OFF_WQH  = (size_t)40*1024*1024;               // 512 KiB f16
static const size_t OFF_WKH  = (size_t)40*1024*1024 + 512*1024;    // 512 KiB f16
static const size_t OFF_KSUM = (size_t)41*1024*1024;               // 16 KiB f32 [8][512] (64K slot)
static const size_t OFF_KVG  = (size_t)41*1024*1024 + 64*1024;     // 1 MiB f32 [64bh][64d][64e]
static const size_t OFF_KVT  = (size_t)42*1024*1024 + 64*1024;     // 512 KiB f16 [64bh][64e][64d]

__device__ __forceinline__ unsigned int pack2h(float a, float b){
    union { _Float16 h[2]; unsigned int u; } x;
    x.h[0] = (_Float16)a; x.h[1] = (_Float16)b; return x.u;
}

// ---- cos/sin tables ----
__global__ void k_tables(float* __restrict__ cosT, float* __restrict__ sinT){
    int n = blockIdx.x, j = threadIdx.x;
    double th = exp((double)j * -0.035977892078031970); // ln(1e4)/256
    float ang = (float)n * (float)th;
    float s, c; sincosf(ang, &s, &c);
    cosT[n*256 + j] = c; sinT[n*256 + j] = s;
}

// ---- weights f32 -> f16 ----
__global__ __launch_bounds__(256) void k_prepw(const float* __restrict__ Wq, const float* __restrict__ Wk,
                                               _Float16* __restrict__ Wqh, _Float16* __restrict__ Wkh){
    int u = blockIdx.x*256 + threadIdx.x;   // 32768 units of 8
    {
        float4 a = *(const float4*)&Wq[(size_t)u*8];
        float4 b = *(const float4*)&Wq[(size_t)u*8 + 4];
        uint4 o; o.x = pack2h(a.x,a.y); o.y = pack2h(a.z,a.w); o.z = pack2h(b.x,b.y); o.w = pack2h(b.z,b.w);
        *(uint4*)&Wqh[(size_t)u*8] = o;
    }
    {
        float4 a = *(const float4*)&Wk[(size_t)u*8];
        float4 b = *(const float4*)&Wk[(size_t)u*8 + 4];
        uint4 o; o.x = pack2h(a.x,a.y); o.y = pack2h(a.z,a.w); o.z = pack2h(b.x,b.y); o.w = pack2h(b.z,b.w);
        *(uint4*)&Wkh[(size_t)u*8] = o;
    }
}

// ---- stage 128x32 f16 tile via global_load_lds, swizzled source / linear dest ----
// phys 16B-unit p = r*4 + (c8 ^ s(r)), s(r) = (r ^ (r>>2)) & 3
__device__ __forceinline__ void stage_b(const _Float16* __restrict__ g, _Float16* lds, int t){
#pragma unroll
    for (int i=0;i<2;++i){
        int u = i*256 + t;
        int r = u >> 2;
        int c8 = (u & 3) ^ ((r ^ (r >> 2)) & 3);
        __builtin_amdgcn_global_load_lds(
            (const __attribute__((address_space(1))) void*)(g + (size_t)r*C_ + c8*8),
            (__attribute__((address_space(3))) void*)(lds + (size_t)(i*256 + (t & 192))*8),
            16, 0, 0);
    }
}

// ---- fused GEMM: IS_Q=0: k path (-> krh, ksum); IS_Q=1: q path (fused z, qr@kv, lepe, out) ----
template<int IS_Q>
__global__ __launch_bounds__(256, 2) void k_gemm(
    const float* __restrict__ X, const _Float16* __restrict__ Wh, const float* __restrict__ bias,
    const float* __restrict__ cosT, const float* __restrict__ sinT,
    _Float16* __restrict__ krh, float* __restrict__ ksum,
    const float* __restrict__ ksumIn, const _Float16* __restrict__ kvTg,
    const float* __restrict__ y, const float* __restrict__ lw, const float* __restrict__ lb,
    float* __restrict__ outp)
{
    __shared__ __align__(16) char smem[IS_Q ? 55296 : 26624];
    _Float16* As  = (_Float16*)smem;              // [128][40] padded
    _Float16* Bs0 = (_Float16*)(smem + 10240);    // [128][32] linear swizzled
    _Float16* Bs1 = (_Float16*)(smem + 18432);
    _Float16* qrs = (_Float16*)smem;              // alias (epilogue): 4 waves x [64][72]
    _Float16* kvs = (_Float16*)(smem + 36864);    // 2 heads x [64][72]

    const int t = threadIdx.x;
    const int lane = t & 63;
    const int w = t >> 6;
    const int wm = w >> 1, wn = w & 1;
    const int col0 = blockIdx.x * 128;
    const int row0 = blockIdx.y * 128;
    const int lrow = lane & 15, lg = lane >> 4;
    const int srow = t >> 3;
    const int sc4 = (t & 7) * 4;
    const int b = row0 >> 12;

    if constexpr (IS_Q){
        // stage kv tiles for this block's two heads: kvTg[bh][e][d] -> kvs[hl][e][72]
#pragma unroll
        for (int i=0;i<4;++i){
            int idx = i*256 + t;
            int hl = idx >> 9, e = (idx >> 3) & 63, c8 = idx & 7;
            int bhh = b*H_ + (col0 >> 6) + hl;
            *(uint4*)&kvs[hl*4608 + e*72 + c8*8] =
                *(const uint4*)&kvTg[(size_t)bhh*4096 + e*64 + c8*8];
        }
    }

    f4 acc[4][4] = {};
    const float* Xp = X + (size_t)(row0 + srow)*C_ + sc4;
    float4 ra[4];
#pragma unroll
    for (int it=0; it<4; ++it) ra[it] = *(const float4*)(Xp + (size_t)it*32*C_);
    stage_b(Wh + (size_t)col0*C_, Bs0, t);

    const int sw = (lrow ^ (lrow >> 2)) & 3;
    const int cB = (lg ^ sw) * 8;
    _Float16* Bcur = Bs0; _Float16* Bnxt = Bs1;

    for (int kk=0; kk<16; ++kk){
#pragma unroll
        for (int it=0; it<4; ++it){
            int r = srow + it*32;
            h4v a; a[0]=(_Float16)ra[it].x; a[1]=(_Float16)ra[it].y; a[2]=(_Float16)ra[it].z; a[3]=(_Float16)ra[it].w;
            *(h4v*)&As[r*40 + sc4] = a;
        }
        if (kk < 15){
#pragma unroll
            for (int it=0; it<4; ++it)
                ra[it] = *(const float4*)(Xp + (size_t)it*32*C_ + (kk+1)*32);
            stage_b(Wh + (size_t)col0*C_ + (kk+1)*32, Bnxt, t);
        }
        __syncthreads();
        h8 af[4], bf[4];
#pragma unroll
        for (int mi=0; mi<4; ++mi) af[mi] = *(const h8*)&As[(wm*64 + mi*16 + lrow)*40 + lg*8];
#pragma unroll
        for (int ni=0; ni<4; ++ni) bf[ni] = *(const h8*)&Bcur[(wn*64 + ni*16 + lrow)*32 + cB];
#pragma unroll
        for (int mi=0; mi<4; ++mi)
#pragma unroll
            for (int ni=0; ni<4; ++ni)
                acc[mi][ni] = __builtin_amdgcn_mfma_f32_16x16x32_f16(af[mi], bf[ni], acc[mi][ni], 0,0,0);
        __syncthreads();
        _Float16* tmp = Bcur; Bcur = Bnxt; Bnxt = tmp;
    }

    // ---- epilogue ----
    const int hcol0 = col0 + wn*64;
    float bcol[4], km[4];
#pragma unroll
    for (int ni=0; ni<4; ++ni){
        int c = hcol0 + ni*16 + lrow;
        bcol[ni] = bias[c];
        km[ni] = IS_Q ? ksumIn[b*C_ + c] * (1.0f/4096.0f) : 0.0f;
    }
    float colsum[4] = {0.f,0.f,0.f,0.f};
    float zr[4][4];
    _Float16* qw = qrs + w*4608;   // wave-local [64][72]

#pragma unroll
    for (int mi=0; mi<4; ++mi){
        float qv[4][4];
#pragma unroll
        for (int ni=0; ni<4; ++ni)
#pragma unroll
            for (int r=0; r<4; ++r){
                float v = acc[mi][ni][r] + bcol[ni];
                qv[ni][r] = v > 0.f ? v + 1.f : __expf(v);   // elu+1
            }
        if constexpr (IS_Q){
#pragma unroll
            for (int r=0; r<4; ++r){
                float p = qv[0][r]*km[0] + qv[1][r]*km[1] + qv[2][r]*km[2] + qv[3][r]*km[3];
                p += __shfl_xor(p, 1); p += __shfl_xor(p, 2);
                p += __shfl_xor(p, 4); p += __shfl_xor(p, 8);
                zr[mi][r] = 1.0f / (p + 1e-6f);
            }
        } else {
#pragma unroll
            for (int ni=0; ni<4; ++ni)
                colsum[ni] += qv[ni][0]+qv[ni][1]+qv[ni][2]+qv[ni][3];
        }
        // rope
#pragma unroll
        for (int ni=0; ni<4; ++ni){
            int c = hcol0 + ni*16 + lrow;
            int jj = c >> 1;
#pragma unroll
            for (int r=0; r<4; ++r){
                int grow = row0 + wm*64 + mi*16 + lg*4 + r;
                int n = grow & (N_-1);
                float val = qv[ni][r];
                float par = __shfl_xor(val, 1);
                float cs = cosT[n*256 + jj], sn = sinT[n*256 + jj];
                float rv = (lane & 1) ? fmaf(sn, par, cs*val) : fmaf(cs, val, -sn*par);
                float prv = __shfl_xor(rv, 1);
                if constexpr (IS_Q){
                    if (!(lane & 1))
                        *(unsigned int*)&qw[(mi*16 + lg*4 + r)*72 + (ni*16 + lrow)] = pack2h(rv, prv);
                } else {
                    if (!(lane & 1))
                        *(unsigned int*)&krh[(size_t)grow*C_ + c] = pack2h(rv, prv);
                }
            }
        }
    }

    if constexpr (!IS_Q){
#pragma unroll
        for (int ni=0; ni<4; ++ni){
            float s = colsum[ni];
            s += __shfl_xor(s, 16); s += __shfl_xor(s, 32);
            if (lane < 16) atomicAdd(&ksum[b*C_ + hcol0 + ni*16 + lane], s);
        }
    } else {
        // wave-local out-gemm: out[64n x 64e] = qr(64x64) @ kv(64x64)
        f4 acc2[4][4] = {};
#pragma unroll
        for (int ks=0; ks<2; ++ks){
            h8 af2[4], bf2[4];
#pragma unroll
            for (int mi2=0; mi2<4; ++mi2) af2[mi2] = *(const h8*)&qw[(mi2*16 + lrow)*72 + ks*32 + lg*8];
#pragma unroll
            for (int ni2=0; ni2<4; ++ni2) bf2[ni2] = *(const h8*)&kvs[wn*4608 + (ni2*16 + lrow)*72 + ks*32 + lg*8];
#pragma unroll
            for (int mi2=0; mi2<4; ++mi2)
#pragma unroll
                for (int ni2=0; ni2<4; ++ni2)
                    acc2[mi2][ni2] = __builtin_amdgcn_mfma_f32_16x16x32_f16(af2[mi2], bf2[ni2], acc2[mi2][ni2], 0,0,0);
        }
        // lepe weights
        float w0[4], w1[4], w2[4], wb[4];
#pragma unroll
        for (int ni2=0; ni2<4; ++ni2){
            int cc = hcol0 + ni2*16 + lrow;
            w0[ni2]=lw[cc*3+0]; w1[ni2]=lw[cc*3+1]; w2[ni2]=lw[cc*3+2]; wb[ni2]=lb[cc];
        }
#pragma unroll
        for (int mi2=0; mi2<4; ++mi2){
#pragma unroll
            for (int r=0; r<4; ++r){
                int grow = row0 + wm*64 + mi2*16 + lg*4 + r;
                int n = grow & (N_-1);
                float z = zr[mi2][r];
#pragma unroll
                for (int ni2=0; ni2<4; ++ni2){
                    int c = hcol0 + ni2*16 + lrow;
                    const float* yp = y + (size_t)grow*C_ + c;
                    float s = fmaf(yp[0], w1[ni2], wb[ni2]);
                    if (n > 0)      s = fmaf(*(yp - C_), w0[ni2], s);
                    if (n < N_-1)   s = fmaf(*(yp + C_), w2[ni2], s);
                    outp[(size_t)grow*C_ + c] = fmaf(acc2[mi2][ni2][r], z, s);
                }
            }
        }
    }
}

// ---- kv = (1/N) k_rope^T @ v : LDS-transposed tiles, chunk-XOR swizzle, atomic f32 partials ----
__global__ __launch_bounds__(256) void k_kv(const _Float16* __restrict__ krh, const float* __restrict__ y,
                                            float* __restrict__ kvg){
    __shared__ _Float16 krs[64*128];   // [64 d][16 units], unit p = d*16 + (chunk ^ (d&15))
    __shared__ _Float16 vs[64*128];
    const int split = blockIdx.x, bh = blockIdx.y;
    const int b = bh >> 3, h = bh & 7;
    const int t = threadIdx.x, lane = t & 63, w = t >> 6;
    const int lrow = lane & 15, lg = lane >> 4;
    f4 acc[4] = {};
    for (int sub=0; sub<4; ++sub){
        const int n0 = split*512 + sub*128;
#pragma unroll
        for (int i=0;i<8;++i){
            int q = i*256 + t;
            int d2 = q & 31, n2 = q >> 5;
            int n = n0 + 2*n2, c = h*64 + 2*d2;
            size_t g0 = (size_t)(b*N_ + n)*C_ + c;
            unsigned int u0 = *(const unsigned int*)&krh[g0];
            unsigned int u1 = *(const unsigned int*)&krh[g0 + C_];
            int chunk = n2 >> 2, j2 = (n2 & 3)*2;
            int pc0 = chunk ^ ((2*d2) & 15);
            int pc1 = pc0 ^ 1;
            *(unsigned int*)&krs[(2*d2)*128 + pc0*8 + j2]   = (u0 & 0xffffu) | (u1 << 16);
            *(unsigned int*)&krs[(2*d2+1)*128 + pc1*8 + j2] = (u0 >> 16) | (u1 & 0xffff0000u);
            float2 a0 = *(const float2*)&y[g0];
            float2 a1 = *(const float2*)&y[g0 + C_];
            *(unsigned int*)&vs[(2*d2)*128 + pc0*8 + j2]   = pack2h(a0.x, a1.x);
            *(unsigned int*)&vs[(2*d2+1)*128 + pc1*8 + j2] = pack2h(a0.y, a1.y);
        }
        __syncthreads();
#pragma unroll
        for (int ks=0; ks<4; ++ks){
            int cu = ((ks*4 + lg) ^ lrow)*8;
            h8 a = *(const h8*)&krs[(w*16 + lrow)*128 + cu];
#pragma unroll
            for (int ni=0; ni<4; ++ni){
                h8 bv = *(const h8*)&vs[(ni*16 + lrow)*128 + cu];
                acc[ni] = __builtin_amdgcn_mfma_f32_16x16x32_f16(a, bv, acc[ni], 0,0,0);
            }
        }
        __syncthreads();
    }
#pragma unroll
    for (int ni=0; ni<4; ++ni)
#pragma unroll
        for (int rr=0; rr<4; ++rr)
            atomicAdd(&kvg[(size_t)bh*4096 + (w*16 + lg*4 + rr)*64 + ni*16 + lrow],
                      acc[ni][rr] * (1.0f/4096.0f));
}

// ---- kvg f32 [bh][d][e] -> kvTg f16 [bh][e][d] ----
__global__ __launch_bounds__(256) void k_kvmerge(const float* __restrict__ kvg, _Float16* __restrict__ kvTg){
    int bh = blockIdx.x, t = threadIdx.x;
    const float* src = kvg + (size_t)bh*4096;
    _Float16* dst = kvTg + (size_t)bh*4096;
#pragma unroll
    for (int i=0;i<4;++i){
        int q = i*256 + t;
        int e2 = q & 31, d2 = q >> 5;
        float2 a0 = *(const float2*)&src[(2*d2)*64 + 2*e2];
        float2 a1 = *(const float2*)&src[(2*d2+1)*64 + 2*e2];
        *(unsigned int*)&dst[(2*e2)*64 + 2*d2]   = pack2h(a0.x, a1.x);
        *(unsigned int*)&dst[(2*e2+1)*64 + 2*d2] = pack2h(a0.y, a1.y);
    }
}

extern "C" void kernel_launch(void* const* d_in, const int* in_sizes, int n_in,
                              void* d_out, int out_size, void* d_ws, size_t ws_size,
                              hipStream_t stream)
{
    (void)in_sizes; (void)n_in; (void)out_size; (void)ws_size;
    const float* x  = (const float*)d_in[0];
    const float* y  = (const float*)d_in[1];
    const float* Wq = (const float*)d_in[2];
    const float* bq = (const float*)d_in[3];
    const float* Wk = (const float*)d_in[4];
    const float* bk = (const float*)d_in[5];
    const float* lw = (const float*)d_in[6];
    const float* lb = (const float*)d_in[7];

    char* ws = (char*)d_ws;
    float*    cosT = (float*)(ws + OFF_COS);
    float*    sinT = (float*)(ws + OFF_SIN);
    _Float16* krh  = (_Float16*)(ws + OFF_KRH);
    _Float16* Wqh  = (_Float16*)(ws + OFF_WQH);
    _Float16* Wkh  = (_Float16*)(ws + OFF_WKH);
    float*    ksum = (float*)(ws + OFF_KSUM);
    float*    kvg  = (float*)(ws + OFF_KVG);
    _Float16* kvTg = (_Float16*)(ws + OFF_KVT);
    float*    out  = (float*)d_out;

    hipMemsetAsync(ws + OFF_KSUM, 0, 64*1024 + 1024*1024, stream);
    k_tables<<<dim3(N_), dim3(256), 0, stream>>>(cosT, sinT);
    k_prepw<<<dim3(128), dim3(256), 0, stream>>>(Wq, Wk, Wqh, Wkh);
    k_gemm<0><<<dim3(4, 256), dim3(256), 0, stream>>>(y, Wkh, bk, cosT, sinT,
        krh, ksum, nullptr, nullptr, nullptr, nullptr, nullptr, nullptr);
    k_kv<<<dim3(8, 64), dim3(256), 0, stream>>>(krh, y, kvg);
    k_kvmerge<<<dim3(64), dim3(256), 0, stream>>>(kvg, kvTg);
    k_gemm<1><<<dim3(4, 256), dim3(256), 0, stream>>>(x, Wqh, bq, cosT, sinT,
        nullptr, nullptr, ksum, kvTg, y, lw, lb, out);
}